// Round 15
// baseline (1244.482 us; speedup 1.0000x reference)
//
#include <hip/hip_runtime.h>

// MHSA with relative position bias (Swin window attention), MI355X gfx950.
// B=2048 windows, N=49 tokens, C=1024, 16 heads x 64. fp16 MFMA, fp32 accum.
// Round 15: attn = 2 waves sharing one 16KB LDS block (wave w owns Q-rows
// [32w,32w+32); K+Vt shared, staged split; P split 2x4KB over dead K space)
// -> 20 waves/CU (was 10) for a BW-bound streaming kernel at 60% fill.
// All global loads stay hoisted (R10 discipline); exactly 2 __syncthreads.
// GEMMs = Round-2 schedule + head-blocked boundary layouts (settled).
// cvt: 3 launches merged into 1 grid-stride kernel.

typedef _Float16 f16;
typedef _Float16 f16x8 __attribute__((ext_vector_type(8)));
typedef _Float16 f16x4 __attribute__((ext_vector_type(4)));
typedef float f32x4 __attribute__((ext_vector_type(4)));

#define G1P(p) ((const __attribute__((address_space(1))) unsigned int*)(p))
#define L3P(p) ((__attribute__((address_space(3))) unsigned int*)(p))

// ---------------- fp32 -> fp16 convert (merged: x, qkv_w, proj_w) ----------------
__global__ void cvt_all(const float* __restrict__ x, const float* __restrict__ wq,
                        const float* __restrict__ wp, f16* __restrict__ x16,
                        f16* __restrict__ wq16, f16* __restrict__ wp16) {
  int i = blockIdx.x * blockDim.x + threadIdx.x;
  int stride = gridDim.x * blockDim.x;
  for (; i < 26738688; i += stride) {   // 25690112 + 786432 + 262144 float4s
    const float4* src; f16x4* dst; int off;
    if (i < 25690112) { src = (const float4*)x; dst = (f16x4*)x16; off = i; }
    else if (i < 26476544) { src = (const float4*)wq; dst = (f16x4*)wq16; off = i - 25690112; }
    else { src = (const float4*)wp; dst = (f16x4*)wp16; off = i - 26476544; }
    float4 v = src[off];
    f16x4 o = { (f16)v.x, (f16)v.y, (f16)v.z, (f16)v.w };
    dst[off] = o;
  }
}

// ---------------- bias table: f16 bias_t[h][m][n] = log2e*bias(n,m); mask=-60000 ----
__global__ void bias_kernel(const float* __restrict__ rpb, f16* __restrict__ bias_t) {
  int h = blockIdx.x;
  for (int e = threadIdx.x; e < 4096; e += blockDim.x) {
    int m = e >> 6, n = e & 63;           // TRANSPOSED storage: [m][n]
    float v = -60000.f;                   // exp2(x-60000) == 0 in f32
    if (n < 49 && m < 49) {
      int in_ = n / 7, jn = n % 7, im = m / 7, jm = m % 7;
      v = rpb[h * 169 + (im - in_ + 6) * 13 + (jm - jn + 6)] * 1.44269504f;
    }
    bias_t[h * 4096 + e] = (f16)v;
  }
}

// ---------------- 256x256 8-phase GEMM (Round-2 schedule; best measured) ----------
#define VM4 asm volatile("s_waitcnt vmcnt(4)" ::: "memory")
#define VM0 asm volatile("s_waitcnt vmcnt(0)" ::: "memory")
#define NOVM ((void)0)
#define NOSTG ((void)0)

template <bool HBIN>
__device__ __forceinline__ const f16* aptr(const f16* A, int row, int col, int K) {
  if (HBIN) {
    int bw = row / 49, n = row - bw * 49;
    int h = col >> 6, d = col & 63;
    return A + (size_t)bw * 50176 + h * 3136 + n * 64 + d;
  }
  return A + (size_t)row * K + col;
}

#define STAGEA(ROW0, COL0, LDSOFF)                                                 \
  {                                                                                \
    const f16* s0_ = aptr<HBIN>(A, (ROW0) + wid * 32 + srow, (COL0) + sce, K);     \
    __builtin_amdgcn_global_load_lds(G1P(s0_), L3P(lds + (LDSOFF) + wid * 2048), 16, 0, 0); \
    const f16* s1_ = aptr<HBIN>(A, (ROW0) + wid * 32 + srow + 16, (COL0) + sce, K); \
    __builtin_amdgcn_global_load_lds(G1P(s1_), L3P(lds + (LDSOFF) + wid * 2048 + 1024), 16, 0, 0); \
  }

#define STAGEB(ROW0, COL0, LDSOFF)                                                 \
  {                                                                                \
    const f16* s0_ = B + (size_t)((ROW0) + wid * 32 + srow) * K + ((COL0) + sce);  \
    __builtin_amdgcn_global_load_lds(G1P(s0_), L3P(lds + (LDSOFF) + wid * 2048), 16, 0, 0); \
    const f16* s1_ = s0_ + (size_t)16 * K;                                         \
    __builtin_amdgcn_global_load_lds(G1P(s1_), L3P(lds + (LDSOFF) + wid * 2048 + 1024), 16, 0, 0); \
  }

#define MFMA4(AREG, ROW)                                                           \
  acc[ROW][0] = __builtin_amdgcn_mfma_f32_16x16x32_f16(AREG, b0, acc[ROW][0], 0, 0, 0); \
  acc[ROW][1] = __builtin_amdgcn_mfma_f32_16x16x32_f16(AREG, b1, acc[ROW][1], 0, 0, 0); \
  acc[ROW][2] = __builtin_amdgcn_mfma_f32_16x16x32_f16(AREG, b2, acc[ROW][2], 0, 0, 0); \
  acc[ROW][3] = __builtin_amdgcn_mfma_f32_16x16x32_f16(AREG, b3, acc[ROW][3], 0, 0, 0);

#define PHASE(ABASE, BBASE, MH, STG, VMW)                                          \
  {                                                                                \
    f16x8 a0 = *(const f16x8*)((ABASE) + (wm * 128 + (MH) * 64 +  0 + l15) * 64 + swz); \
    f16x8 a1 = *(const f16x8*)((ABASE) + (wm * 128 + (MH) * 64 + 16 + l15) * 64 + swz); \
    f16x8 a2 = *(const f16x8*)((ABASE) + (wm * 128 + (MH) * 64 + 32 + l15) * 64 + swz); \
    f16x8 a3 = *(const f16x8*)((ABASE) + (wm * 128 + (MH) * 64 + 48 + l15) * 64 + swz); \
    if ((MH) == 0) {                                                               \
      b0 = *(const f16x8*)((BBASE) + (wn * 64 +  0 + l15) * 64 + swz);             \
      b1 = *(const f16x8*)((BBASE) + (wn * 64 + 16 + l15) * 64 + swz);             \
      b2 = *(const f16x8*)((BBASE) + (wn * 64 + 32 + l15) * 64 + swz);             \
      b3 = *(const f16x8*)((BBASE) + (wn * 64 + 48 + l15) * 64 + swz);             \
    }                                                                              \
    STG;                                                                           \
    __builtin_amdgcn_s_barrier();                                                  \
    asm volatile("s_waitcnt lgkmcnt(0)" ::: "memory");                             \
    __builtin_amdgcn_sched_barrier(0);                                             \
    __builtin_amdgcn_s_setprio(1);                                                 \
    MFMA4(a0, (MH) * 4 + 0) MFMA4(a1, (MH) * 4 + 1)                                \
    MFMA4(a2, (MH) * 4 + 2) MFMA4(a3, (MH) * 4 + 3)                                \
    __builtin_amdgcn_s_setprio(0);                                                 \
    VMW;                                                                           \
    __builtin_amdgcn_s_barrier();                                                  \
  }

template <typename OutT, bool HBOUT, bool HBIN>
__global__ __launch_bounds__(512, 2)
void gemm256(const f16* __restrict__ A, const f16* __restrict__ B,
             const float* __restrict__ bias, OutT* __restrict__ C,
             int N, int K, int ntiles_n) {
  __shared__ char lds[131072];
  const int tid = threadIdx.x;
  const int wid = tid >> 6, ln = tid & 63;
  const int l15 = ln & 15, lhi = ln >> 4;
  const int wm = wid >> 2, wn = wid & 3;
  const int srow = ln >> 2;
  const int sce = (((ln & 3) ^ ((ln >> 3) & 3)) << 3);
  const int swz = ((lhi ^ ((l15 >> 1) & 3)) << 4);

  const int nblk = gridDim.x;
  const int wg = (blockIdx.x & 7) * (nblk >> 3) + (blockIdx.x >> 3);
  const int bn = wg % ntiles_n, bm = wg / ntiles_n;
  const int m0 = bm * 256, n0 = bn * 256;

  f32x4 acc[8][4];
#pragma unroll
  for (int i = 0; i < 8; ++i)
#pragma unroll
    for (int j = 0; j < 4; ++j) acc[i][j] = (f32x4){0.f, 0.f, 0.f, 0.f};
  f16x8 b0, b1, b2, b3;

  STAGEA(m0, 0, 0);
  STAGEB(n0, 0, 32768);
  STAGEA(m0, 32, 16384);
  STAGEB(n0, 32, 49152);
  STAGEA(m0, 64, 65536);
  STAGEB(n0, 64, 98304);
  VM4;
  __builtin_amdgcn_s_barrier();

  for (int i = 0; i < 7; ++i) {
    const int cT1k1 = (2 * i + 1) * 64 + 32;
    const int cT2k0 = (2 * i + 2) * 64;
    const int cT2k1 = cT2k0 + 32;
    const int cT3k0 = (2 * i + 3) * 64;
    PHASE(lds + 0,      lds + 32768,  0, STAGEA(m0, cT1k1, 81920),  NOVM);
    PHASE(lds + 0,      lds + 32768,  1, STAGEB(n0, cT1k1, 114688), NOVM);
    PHASE(lds + 16384,  lds + 49152,  0, STAGEA(m0, cT2k0, 0),      NOVM);
    PHASE(lds + 16384,  lds + 49152,  1, STAGEB(n0, cT2k0, 32768),  VM4);
    PHASE(lds + 65536,  lds + 98304,  0, STAGEA(m0, cT2k1, 16384),  NOVM);
    PHASE(lds + 65536,  lds + 98304,  1, STAGEB(n0, cT2k1, 49152),  NOVM);
    PHASE(lds + 81920,  lds + 114688, 0, STAGEA(m0, cT3k0, 65536),  NOVM);
    PHASE(lds + 81920,  lds + 114688, 1, STAGEB(n0, cT3k0, 98304),  VM4);
  }
  PHASE(lds + 0,      lds + 32768,  0, STAGEA(m0, 15 * 64 + 32, 81920),  NOVM);
  PHASE(lds + 0,      lds + 32768,  1, STAGEB(n0, 15 * 64 + 32, 114688), NOVM);
  PHASE(lds + 16384,  lds + 49152,  0, NOSTG, NOVM);
  PHASE(lds + 16384,  lds + 49152,  1, NOSTG, VM0);
  PHASE(lds + 65536,  lds + 98304,  0, NOSTG, NOVM);
  PHASE(lds + 65536,  lds + 98304,  1, NOSTG, NOVM);
  PHASE(lds + 81920,  lds + 114688, 0, NOSTG, NOVM);
  PHASE(lds + 81920,  lds + 114688, 1, NOSTG, NOVM);

  float bv[4];
#pragma unroll
  for (int j = 0; j < 4; ++j) bv[j] = bias[n0 + wn * 64 + j * 16 + l15];
#pragma unroll
  for (int ii = 0; ii < 8; ++ii)
#pragma unroll
    for (int r = 0; r < 4; ++r) {
      int gr = m0 + wm * 128 + ii * 16 + lhi * 4 + r;
      if (HBOUT) {
        int bw = gr / 49, n = gr - bw * 49;   // window, token
#pragma unroll
        for (int j = 0; j < 4; ++j) {
          int gc = n0 + wn * 64 + j * 16 + l15;
          int which = gc >> 10, rem = gc & 1023;
          int h = rem >> 6, d = rem & 63;
          size_t addr = (((size_t)bw * 16 + h) * 3 + which) * 3136 + n * 64 + d;
          C[addr] = (OutT)(acc[ii][j][r] + bv[j]);
        }
      } else {
#pragma unroll
        for (int j = 0; j < 4; ++j) {
          int gc = n0 + wn * 64 + j * 16 + l15;
          C[(size_t)gr * N + gc] = (OutT)(acc[ii][j][r] + bv[j]);
        }
      }
    }
}

// ---------------- attention: 2 waves per (window, head), shared 16KB LDS ----------
// Wave w owns Q-rows [32w, 32w+32). LDS: K [0,8K) -> P (2 x 4KB) after barrier 2;
// Vt [8K,16K). Staging split: wave w stages K slots 4w..4w+3 and transposes V
// d-cols [32w,32w+32). All global loads hoisted; exactly two __syncthreads.
__global__ __launch_bounds__(128)
void attn_kernel(const f16* __restrict__ qkv,        // [b][h][q|k|v][49][64]
                 const f16* __restrict__ bias_t,     // f16 [16][m][n], pre-scaled log2e
                 f16* __restrict__ out) {             // [b][h][49][64]
  __shared__ char lds[16384];
  const int bh = blockIdx.x;
  const int h = bh & 15;
  const int tid = threadIdx.x;
  const int w = tid >> 6, ln = tid & 63;
  const int l15 = ln & 15, lhi = ln >> 4;
  const size_t qb = (size_t)bh * 9408;       // 3*3136
  const size_t kb = qb + 3136, vb = qb + 6272;
  const int nb = w * 32;                     // this wave's Q-row base

  // --- issue K staging (4x global_load_lds per wave; contiguous 128B rows) ---
  {
    int rA = ln >> 3, lc = ln & 7;
#pragma unroll
    for (int cc = 0; cc < 4; ++cc) {
      int c = w * 4 + cc;
      int r = c * 8 + rA;
      int rc = r > 48 ? 48 : r;
      int ce = (lc ^ (r & 7)) << 3;
      const f16* g = qkv + kb + rc * 64 + ce;
      __builtin_amdgcn_global_load_lds(G1P(g), L3P(lds + c * 1024), 16, 0, 0);
    }
  }

  // --- issue V loads (4x b128 per wave: row ln, d-cols [nb, nb+32)) ---
  int rv = ln > 48 ? 48 : ln;
  const f16* vp = qkv + vb + rv * 64 + nb;
  f16x8 vr[4];
#pragma unroll
  for (int j = 0; j < 4; ++j) vr[j] = *(const f16x8*)(vp + j * 8);

  // --- issue Q loads (4x b128: rows nb + t*16 + l15) ---
  f16x8 qf[2][2];
#pragma unroll
  for (int t = 0; t < 2; ++t) {
    int rq = nb + t * 16 + l15;
    if (rq > 48) rq = 48;
    const f16* qp = qkv + qb + rq * 64 + lhi * 8;
    qf[t][0] = *(const f16x8*)(qp);
    qf[t][1] = *(const f16x8*)(qp + 32);
  }

  // --- issue bias loads (8x f16x4): bq[i][j] = bias[m=j*16+l15][n=nb+i*16+lhi*4..+4) ---
  const f16* bb = bias_t + h * 4096;
  f16x4 bq[2][4];
#pragma unroll
  for (int i = 0; i < 2; ++i)
#pragma unroll
    for (int j = 0; j < 4; ++j)
      bq[i][j] = *(const f16x4*)(bb + (j * 16 + l15) * 64 + nb + i * 16 + lhi * 4);

  // --- V transpose into Vt (32 scalar writes per lane) ---
#pragma unroll
  for (int dd = 0; dd < 32; ++dd) {
    int d = nb + dd;
    *(f16*)(lds + 8192 + d * 128 + ((ln * 2) ^ ((d & 7) << 4))) = vr[dd >> 3][dd & 7];
  }

  __syncthreads();   // barrier 1: K staged (vmcnt0) + Vt written, both waves

  // --- S = Q @ K^T (K frags from shared LDS) ---
  f32x4 acc[2][4];
#pragma unroll
  for (int i = 0; i < 2; ++i)
#pragma unroll
    for (int j = 0; j < 4; ++j) acc[i][j] = (f32x4){0.f, 0.f, 0.f, 0.f};
#pragma unroll
  for (int kk = 0; kk < 2; ++kk) {
    f16x8 bf[4];
#pragma unroll
    for (int t = 0; t < 4; ++t) {
      int mr = t * 16 + l15;
      int pb = (kk * 64 + lhi * 16) ^ ((mr & 7) << 4);
      bf[t] = *(const f16x8*)(lds + mr * 128 + pb);
    }
    __builtin_amdgcn_s_setprio(1);
#pragma unroll
    for (int i = 0; i < 2; ++i)
#pragma unroll
      for (int j = 0; j < 4; ++j)
        acc[i][j] = __builtin_amdgcn_mfma_f32_16x16x32_f16(qf[i][kk], bf[j], acc[i][j], 0, 0, 0);
    __builtin_amdgcn_s_setprio(0);
  }

  __syncthreads();   // barrier 2: all K reads done -> P may overwrite K space

  // --- softmax (base-2; bias in regs); P into own 4KB half of K space ---
  const float SC = 0.125f * 1.44269504f;
  char* pbase = lds + w * 4096;
#pragma unroll
  for (int i = 0; i < 2; ++i) {
#pragma unroll
    for (int r = 0; r < 4; ++r) {
      int nl = i * 16 + lhi * 4 + r;          // local row 0..31
      float lv[4];
#pragma unroll
      for (int j = 0; j < 4; ++j)
        lv[j] = acc[i][j][r] * SC + (float)bq[i][j][r];
      float Mx = fmaxf(fmaxf(lv[0], lv[1]), fmaxf(lv[2], lv[3]));
#pragma unroll
      for (int off = 1; off < 16; off <<= 1) Mx = fmaxf(Mx, __shfl_xor(Mx, off));
      float s = 0.f;
#pragma unroll
      for (int j = 0; j < 4; ++j) { lv[j] = exp2f(lv[j] - Mx); s += lv[j]; }
#pragma unroll
      for (int off = 1; off < 16; off <<= 1) s += __shfl_xor(s, off);
      float inv = 1.f / s;
#pragma unroll
      for (int j = 0; j < 4; ++j) {
        int m = j * 16 + l15;
        *(f16*)(pbase + nl * 128 + ((m * 2) ^ ((nl & 7) << 4))) = (f16)(lv[j] * inv);
      }
    }
  }
  // per-wave in-order DS: own P writes retire before own P reads below

  // --- O = P @ V ---
  f32x4 o[2][4];
#pragma unroll
  for (int i = 0; i < 2; ++i)
#pragma unroll
    for (int j = 0; j < 4; ++j) o[i][j] = (f32x4){0.f, 0.f, 0.f, 0.f};
#pragma unroll
  for (int kk = 0; kk < 2; ++kk) {
    f16x8 af[2], bf[4];
#pragma unroll
    for (int t = 0; t < 2; ++t) {
      int nl = t * 16 + l15;
      af[t] = *(const f16x8*)(pbase + nl * 128 + ((kk * 64 + lhi * 16) ^ ((nl & 7) << 4)));
    }
#pragma unroll
    for (int u = 0; u < 4; ++u) {
      int dr = u * 16 + l15;
      bf[u] = *(const f16x8*)(lds + 8192 + dr * 128 + ((kk * 64 + lhi * 16) ^ ((dr & 7) << 4)));
    }
    __builtin_amdgcn_s_setprio(1);
#pragma unroll
    for (int i = 0; i < 2; ++i)
#pragma unroll
      for (int j = 0; j < 4; ++j)
        o[i][j] = __builtin_amdgcn_mfma_f32_16x16x32_f16(af[i], bf[j], o[i][j], 0, 0, 0);
    __builtin_amdgcn_s_setprio(0);
  }
  // store head-blocked: one contiguous 6.2KB run per block
  f16* ob = out + (size_t)bh * 3136;
#pragma unroll
  for (int i = 0; i < 2; ++i)
#pragma unroll
    for (int j = 0; j < 4; ++j)
#pragma unroll
      for (int r = 0; r < 4; ++r) {
        int n = nb + i * 16 + lhi * 4 + r;
        if (n < 49)
          ob[n * 64 + j * 16 + l15] = (f16)o[i][j][r];
      }
}

extern "C" void kernel_launch(void* const* d_in, const int* in_sizes, int n_in,
                              void* d_out, int out_size, void* d_ws, size_t ws_size,
                              hipStream_t stream) {
  const float* x      = (const float*)d_in[0];  // [100352][1024]
  const float* qkv_w  = (const float*)d_in[1];  // [3072][1024]
  const float* qkv_b  = (const float*)d_in[2];  // [3072]
  const float* rpb    = (const float*)d_in[3];  // [16][13][13]
  const float* proj_w = (const float*)d_in[4];  // [1024][1024]
  const float* proj_b = (const float*)d_in[5];  // [1024]
  float* out = (float*)d_out;

  char* ws = (char*)d_ws;
  f16*   x16      = (f16*)(ws);                              // 205,520,896
  f16*   wq16     = (f16*)(ws + 205520896);                  //   6,291,456
  f16*   wp16     = (f16*)(ws + 211812352);                  //   2,097,152
  f16*   qkv16    = (f16*)(ws + 213909504);                  // 616,562,688 (head-blocked)
  f16*   attnHB   = (f16*)(ws + 830472192);                  // 205,520,896 (head-blocked)
  f16*   bias_t   = (f16*)(ws + 1035993088);                 //     131,072

  cvt_all<<<2048, 256, 0, stream>>>(x, qkv_w, proj_w, x16, wq16, wp16);
  bias_kernel<<<16, 64, 0, stream>>>(rpb, bias_t);

  // qkv = x @ qkv_w^T + qkv_b -> head-blocked [b][h][q|k|v][49][64] fp16
  gemm256<f16, true, false><<<4704, 512, 0, stream>>>(x16, wq16, qkv_b, qkv16, 3072, 1024, 12);
  // attention: 2 waves per (window, head); HB in, HB out
  attn_kernel<<<2048 * 16, 128, 0, stream>>>(qkv16, bias_t, attnHB);
  // out = attnHB @ proj_w^T + proj_b   [100352][1024] fp32 (HB A-read)
  gemm256<float, false, true><<<1568, 512, 0, stream>>>(attnHB, wp16, proj_b, out, 1024, 1024, 4);
}